// Round 14
// baseline (30.073 us; speedup 1.0000x reference)
//
#include <hip/hip_runtime.h>
#include <hip/hip_bf16.h>

namespace {

typedef short bf16x8 __attribute__((ext_vector_type(8), may_alias));
typedef float f32x4_ma __attribute__((ext_vector_type(4), may_alias));
typedef __attribute__((ext_vector_type(16))) float f32x16;   // MFMA 32x32 acc

constexpr int kB = 32, kT = 16384, kCin = 32, kCout = 32;
constexpr int kL = 128;            // owned rows per chunk
constexpr int kK = 32;             // zero-state warm-up
constexpr int kChunks = kT / kL;   // 128
constexpr int kWpB = 4;            // waves per block
constexpr int kRows = 34;          // stage rows (32 + 2 halo)
constexpr int kStageF = kRows * kCin;      // 1088 floats = 4352 B per stage
constexpr int kNT = 5;             // 1 warm-up tile + 4 owned tiles
constexpr int kTS = 36;            // transpose-buffer row stride (floats)
constexpr int kTBufF = 32 * kTS;   // 1152 floats

__device__ __forceinline__ short f2bf(float f) {
  return (short)__builtin_bit_cast(unsigned short, __float2bfloat16(f));
}

// Fire-and-forget global->LDS DMA, 16B per lane. LDS dest = uniform base +
// lane*16 (linear, m104); global src is PER-LANE, so the bank swizzle is
// applied by permuting the source addresses (m173).
__device__ __forceinline__ void dma16(const float* g, float* l) {
  __builtin_amdgcn_global_load_lds(
      (__attribute__((address_space(1))) void*)(uintptr_t)g,
      (__attribute__((address_space(3))) void*)l, 16, 0, 0);
}

#define VMWAIT(N)                                            \
  do {                                                       \
    asm volatile("s_waitcnt vmcnt(" #N ")" ::: "memory");    \
    __builtin_amdgcn_sched_barrier(0);                       \
  } while (0)

// Wave = one (b, chunk). u staged by global_load_lds DMA into 3 f32 LDS
// buffers (depth-2 prefetch, counted vmcnt waits, never 0 mid-loop). LDS
// chunk-XOR swizzle (c ^= row&7) applied via pre-swizzled per-lane global
// source + same XOR on ds_read -> 8-way instead of 32-way conflicts.
// FIR = 12x ds_read_b128 f32 + cvt + 6 MFMA; IIR + transpose-store = R13.
__global__ __launch_bounds__(256, 2) void mimo_dma(
    const float* __restrict__ u,        // [B, T, CIN]
    const float* __restrict__ x0,       // [B, 2, COUT]
    const float* __restrict__ a_coeff,  // [2, COUT]
    const float* __restrict__ b_coeff,  // [3, CIN, COUT]
    float* __restrict__ out)            // [B, T, COUT]
{
  __shared__ float stg[kWpB][3][kStageF];   // 51 KiB (3 stage bufs / wave)
  __shared__ float tbf[kWpB][kTBufF];       // 18 KiB

  const int tidx = (int)threadIdx.x;
  const int lane = tidx & 63;
  const int col  = lane & 31;          // output channel / time-row within tile
  const int g    = lane >> 5;          // lane-half
  const int widx = tidx >> 6;
  const int wid  = (int)blockIdx.x * kWpB + widx;
  const int b     = wid >> 7;          // 0..31
  const int chunk = wid & (kChunks - 1);
  const int t0     = chunk * kL;
  const int tstart = t0 - kK;          // chunk 0 warms over zero-pad

  float* Tw = &tbf[widx][0];

  // B fragments: slot (g,j) of K-step (tau,h) = b_coeff[2-tau][16g+8h+j][col].
  // A uses the SAME slot->channel map, so the HW k-order cancels.
  bf16x8 Bf[3][2];
#pragma unroll
  for (int tau = 0; tau < 3; ++tau)
#pragma unroll
    for (int h = 0; h < 2; ++h) {
      const float* bp = b_coeff + (size_t)(2 - tau) * kCin * kCout
                        + (16 * g + 8 * h) * kCout + col;
      bf16x8 fr;
#pragma unroll
      for (int j = 0; j < 8; ++j) fr[j] = f2bf(bp[j * kCout]);
      Bf[tau][h] = fr;
    }

  const float a1 = a_coeff[col];
  const float a2 = a_coeff[kCout + col];
  float i1 = 0.f, i2 = 0.f;            // chunk-0 exact state (injected @t0)
  if (chunk == 0) {
    i1 = x0[(b * 2 + 1) * kCout + col];
    i2 = x0[(b * 2 + 0) * kCout + col];
  }
  float s1 = 0.f, s2 = 0.f;

  const float* ub = u + (size_t)b * kT * kCin;
  float* ob = out + (size_t)b * kT * kCout;

  // DMA one 34-row stage. LDS position p (16B chunks) holds logical chunk
  // (p&~7) | ((p&7) ^ (row&7)) — i.e. source pre-swizzled, dest linear.
  auto dma_stage = [&](float* buf, int rowbase) {
#pragma unroll
    for (int k = 0; k < 4; ++k) {
      const int p = k * 64 + lane;
      const int row = p >> 3;
      const int grow = rowbase + row;
      const int src = (grow < 0 ? 0 : grow) * kCin + (((p & 7) ^ (row & 7)) << 2);
      dma16(ub + src, buf + k * 256);
    }
    if (lane < 16) {
      const int p = 256 + lane;
      const int row = p >> 3;
      const int grow = rowbase + row;
      const int src = (grow < 0 ? 0 : grow) * kCin + (((p & 7) ^ (row & 7)) << 2);
      dma16(ub + src, buf + 1024);
    }
  };
  // chunk-0 only: rows < 0 must be zero (DMA clamped them to row 0 garbage).
  auto zero_fix = [&](float* buf, int rowbase) {
    const int nch = (-rowbase) * 8;    // whole rows -> swizzle-invariant
    for (int p = lane; p < nch; p += 64) {
      f32x4_ma z; z[0] = 0.f; z[1] = 0.f; z[2] = 0.f; z[3] = 0.f;
      *(f32x4_ma*)(buf + p * 4) = z;
    }
  };

  // -------- prologue: DMA stages 0 and 1 --------
  dma_stage(&stg[widx][0][0], tstart - 2);
  dma_stage(&stg[widx][1][0], tstart - 2 + 32);

#pragma unroll
  for (int tile = 0; tile < kNT; ++tile) {
    // depth-2: issue stage tile+2 (into the buffer tile-1 just finished).
    if (tile + 2 < kNT)
      dma_stage(&stg[widx][(tile + 2) % 3][0], tstart - 2 + 32 * (tile + 2));

    // Counted waits for stage `tile` (younger-op ledger: 5 per DMA burst,
    // 4 global stores per owned tile; never vmcnt(0) mid-loop).
    if (tile == 0)      VMWAIT(10);
    else if (tile == 1) VMWAIT(10);
    else if (tile == 2) VMWAIT(14);
    else if (tile == 3) VMWAIT(13);
    else                VMWAIT(8);

    const int rowbase = tstart - 2 + 32 * tile;
    float* Sf = &stg[widx][tile % 3][0];
    if (chunk == 0 && rowbase < 0) zero_fix(Sf, rowbase);

    // ---- FIR: 12x ds_read_b128 (f32, XOR-swizzled) + cvt + 6 MFMAs ----
    f32x16 acc;
#pragma unroll
    for (int i = 0; i < 16; ++i) acc[i] = 0.f;
#pragma unroll
    for (int tau = 0; tau < 3; ++tau) {
      const int r = col + tau;
      const float* rp = Sf + r * kCin;
      const int rx = r & 7;
#pragma unroll
      for (int h = 0; h < 2; ++h) {
        const int c0 = 4 * g + 2 * h;
        const f32x4_ma lo = *(const f32x4_ma*)(rp + ((c0 ^ rx) << 2));
        const f32x4_ma hi = *(const f32x4_ma*)(rp + (((c0 + 1) ^ rx) << 2));
        bf16x8 fa;
        fa[0] = f2bf(lo[0]); fa[1] = f2bf(lo[1]);
        fa[2] = f2bf(lo[2]); fa[3] = f2bf(lo[3]);
        fa[4] = f2bf(hi[0]); fa[5] = f2bf(hi[1]);
        fa[6] = f2bf(hi[2]); fa[7] = f2bf(hi[3]);
        acc = __builtin_amdgcn_mfma_f32_32x32x16_bf16(fa, Bf[tau][h], acc, 0, 0, 0);
      }
    }

    // chunk-0 exact state injection at the first owned tile.
    if (chunk == 0 && tile == 1) { s1 = i1; s2 = i2; }

    const bool owned = (tile >= 1);
    const int tbase = tstart + 32 * tile;

    // ---- IIR per reg-quad (R11/R13-proven); results to LDS transpose buf.
    // Reg r (half gg) holds row (r&3) + 8*(r>>2) + 4*gg of the tile.
    float x1 = s1, x2 = s2;
#pragma unroll
    for (int q = 0; q < 4; ++q) {
      const float o0 = __shfl_xor(acc[4 * q + 0], 32);
      const float o1 = __shfl_xor(acc[4 * q + 1], 32);
      const float o2 = __shfl_xor(acc[4 * q + 2], 32);
      const float o3 = __shfl_xor(acc[4 * q + 3], 32);
      const float va0 = g ? o0 : acc[4 * q + 0];
      const float va1 = g ? o1 : acc[4 * q + 1];
      const float va2 = g ? o2 : acc[4 * q + 2];
      const float va3 = g ? o3 : acc[4 * q + 3];
      const float ya0 = fmaf(a1, x1,  fmaf(a2, x2,  va0));
      const float ya1 = fmaf(a1, ya0, fmaf(a2, x1,  va1));
      const float ya2 = fmaf(a1, ya1, fmaf(a2, ya0, va2));
      const float ya3 = fmaf(a1, ya2, fmaf(a2, ya1, va3));
      const float vb0 = g ? acc[4 * q + 0] : o0;
      const float vb1 = g ? acc[4 * q + 1] : o1;
      const float vb2 = g ? acc[4 * q + 2] : o2;
      const float vb3 = g ? acc[4 * q + 3] : o3;
      const float yb0 = fmaf(a1, ya3, fmaf(a2, ya2, vb0));
      const float yb1 = fmaf(a1, yb0, fmaf(a2, ya3, vb1));
      const float yb2 = fmaf(a1, yb1, fmaf(a2, yb0, vb2));
      const float yb3 = fmaf(a1, yb2, fmaf(a2, yb1, vb3));
      x2 = yb2; x1 = yb3;
      if (owned) {
        const int rb = 8 * q + 4 * g;   // lane half g writes rows rb..rb+3
        Tw[(rb + 0) * kTS + col] = g ? yb0 : ya0;
        Tw[(rb + 1) * kTS + col] = g ? yb1 : ya1;
        Tw[(rb + 2) * kTS + col] = g ? yb2 : ya2;
        Tw[(rb + 3) * kTS + col] = g ? yb3 : ya3;
      }
    }
    s1 = x1; s2 = x2;

    // ---- emit: 4x ds_read_b128 + 4x full-wave global_store_dwordx4 ----
    if (owned) {
      asm volatile("" ::: "memory");   // transpose writes before reads
#pragma unroll
      for (int p = 0; p < 4; ++p) {
        const f32x4_ma v = *(const f32x4_ma*)
            ((const char*)Tw + (8 * p + (lane >> 3)) * (kTS * 4) + (lane & 7) * 16);
        *(f32x4_ma*)(ob + (size_t)(tbase + 8 * p) * kCout + lane * 4) = v;
      }
      asm volatile("" ::: "memory");   // reads before next tile's writes
    }
  }
}

}  // namespace

extern "C" void kernel_launch(void* const* d_in, const int* in_sizes, int n_in,
                              void* d_out, int out_size, void* d_ws, size_t ws_size,
                              hipStream_t stream) {
  const float* u  = (const float*)d_in[0];
  const float* x0 = (const float*)d_in[1];
  const float* a  = (const float*)d_in[2];
  const float* bb = (const float*)d_in[3];
  float* out = (float*)d_out;

  dim3 grid(kB * kChunks / kWpB);  // 4096 waves / 4 = 1024 blocks
  dim3 block(256);
  hipLaunchKernelGGL(mimo_dma, grid, block, 0, stream, u, x0, a, bb, out);
}